// Round 1
// baseline (324.424 us; speedup 1.0000x reference)
//
#include <hip/hip_runtime.h>
#include <math.h>

// ---- problem constants ----
// x: [8,1,512,512] fp32; patches 8x8 -> per batch 64x64 = 4096 patches, pdim=64
// HID=8, SCALE=8^-0.5. Output [8,512,512,3] fp32.
static constexpr float QSCALE = 0.35355339059327373f * 1.4426950408889634f; // SCALE * log2(e)

// =====================================================================
// Kernel 1: patchify + QKV projection (64 -> 8 x3)
// thread per patch; weights staged in LDS (broadcast reads)
// =====================================================================
__global__ __launch_bounds__(256) void qkv_kernel(
    const float* __restrict__ x,
    const float* __restrict__ Wq, const float* __restrict__ bq,
    const float* __restrict__ Wk, const float* __restrict__ bk,
    const float* __restrict__ Wv, const float* __restrict__ bv,
    float* __restrict__ Q, float* __restrict__ K, float* __restrict__ V)
{
    __shared__ float sW[64*24 + 24];
    for (int i = threadIdx.x; i < 64*24 + 24; i += 256) {
        float w;
        if (i < 1536) {
            int j = i / 24, c = i % 24;
            w = (c < 8) ? Wq[j*8 + c] : (c < 16) ? Wk[j*8 + (c-8)] : Wv[j*8 + (c-16)];
        } else {
            int c = i - 1536;
            w = (c < 8) ? bq[c] : (c < 16) ? bk[c-8] : bv[c-16];
        }
        sW[i] = w;
    }
    __syncthreads();

    int p = blockIdx.x * 256 + threadIdx.x;   // 0..32767 global patch id
    int b    = p >> 12;
    int pidx = p & 4095;
    int pr = pidx >> 6, pc = pidx & 63;
    const float* xb = x + ((size_t)(b*512 + pr*8)) * 512 + (size_t)pc*8;

    float px[64];
    #pragma unroll
    for (int i = 0; i < 8; ++i) {
        float4 a = *(const float4*)(xb + (size_t)i*512);
        float4 c = *(const float4*)(xb + (size_t)i*512 + 4);
        px[i*8+0]=a.x; px[i*8+1]=a.y; px[i*8+2]=a.z; px[i*8+3]=a.w;
        px[i*8+4]=c.x; px[i*8+5]=c.y; px[i*8+6]=c.z; px[i*8+7]=c.w;
    }
    float acc[24];
    #pragma unroll
    for (int o = 0; o < 24; ++o) acc[o] = sW[1536 + o];
    #pragma unroll
    for (int j = 0; j < 64; ++j) {
        float pj = px[j];
        #pragma unroll
        for (int o = 0; o < 24; ++o) acc[o] += pj * sW[j*24 + o];
    }
    size_t base = (size_t)p * 8;
    #pragma unroll
    for (int o = 0; o < 8; ++o) {
        Q[base+o] = acc[o];
        K[base+o] = acc[8+o];
        V[base+o] = acc[16+o];
    }
}

// =====================================================================
// Attention: softmax(Q K^T * SCALE) V, per batch N=4096, D=8.
// Wave handles 8 queries; lanes iterate keys (64 keys/pass, 64 passes).
// Scores are tiny (|s|<~3) -> no max subtraction needed; exp2 domain.
// Q pre-scaled by SCALE*log2e at load.
// grid: 1024 blocks x 256 (4 waves/block, waves independent)
// =====================================================================
__global__ __launch_bounds__(256) void attn_kernel(
    const float* __restrict__ Q, const float* __restrict__ K,
    const float* __restrict__ V, float* __restrict__ O)
{
    int lane = threadIdx.x & 63;
    int wid  = threadIdx.x >> 6;
    int gw   = blockIdx.x * 4 + wid;     // 0..4095
    int b     = gw >> 9;                 // 512 waves per batch
    int qbase = (gw & 511) * 8;          // within-batch query base

    const float* Qb = Q + ((size_t)b * 4096 + qbase) * 8;
    const float* Kb = K + (size_t)b * 4096 * 8;
    const float* Vb = V + (size_t)b * 4096 * 8;

    // replicate the 8 queries (64 floats, wave-uniform) into registers
    float q[8][8];
    #pragma unroll
    for (int i = 0; i < 8; ++i) {
        float4 a = ((const float4*)Qb)[i*2];
        float4 c = ((const float4*)Qb)[i*2+1];
        q[i][0]=a.x*QSCALE; q[i][1]=a.y*QSCALE; q[i][2]=a.z*QSCALE; q[i][3]=a.w*QSCALE;
        q[i][4]=c.x*QSCALE; q[i][5]=c.y*QSCALE; q[i][6]=c.z*QSCALE; q[i][7]=c.w*QSCALE;
    }

    float acc[8][8];
    float lsum[8];
    #pragma unroll
    for (int i = 0; i < 8; ++i) {
        lsum[i] = 0.f;
        #pragma unroll
        for (int d = 0; d < 8; ++d) acc[i][d] = 0.f;
    }

    // software-prefetched key/value stream: lane's key this pass = t*64+lane
    const float4* kp0 = (const float4*)(Kb + (size_t)lane * 8);
    const float4* vp0 = (const float4*)(Vb + (size_t)lane * 8);
    float4 k0 = kp0[0], k1 = kp0[1], v0 = vp0[0], v1 = vp0[1];

    for (int t = 0; t < 64; ++t) {
        float4 nk0, nk1, nv0, nv1;
        if (t < 63) {
            const float4* kn = (const float4*)(Kb + ((size_t)((t+1)*64 + lane)) * 8);
            const float4* vn = (const float4*)(Vb + ((size_t)((t+1)*64 + lane)) * 8);
            nk0 = kn[0]; nk1 = kn[1]; nv0 = vn[0]; nv1 = vn[1];
        }
        #pragma unroll
        for (int qi = 0; qi < 8; ++qi) {
            float s = q[qi][0]*k0.x;
            s += q[qi][1]*k0.y; s += q[qi][2]*k0.z; s += q[qi][3]*k0.w;
            s += q[qi][4]*k1.x; s += q[qi][5]*k1.y; s += q[qi][6]*k1.z; s += q[qi][7]*k1.w;
            float e = exp2f(s);             // score already in log2 domain
            lsum[qi] += e;
            acc[qi][0] += e*v0.x; acc[qi][1] += e*v0.y; acc[qi][2] += e*v0.z; acc[qi][3] += e*v0.w;
            acc[qi][4] += e*v1.x; acc[qi][5] += e*v1.y; acc[qi][6] += e*v1.z; acc[qi][7] += e*v1.w;
        }
        if (t < 63) { k0 = nk0; k1 = nk1; v0 = nv0; v1 = nv1; }
    }

    // merge 64 per-lane partials: butterfly sums, then lane (qi*8+d) owns output
    float rinv[8];
    #pragma unroll
    for (int qi = 0; qi < 8; ++qi) {
        float tsum = lsum[qi];
        #pragma unroll
        for (int m = 32; m >= 1; m >>= 1) tsum += __shfl_xor(tsum, m, 64);
        rinv[qi] = 1.0f / tsum;
    }
    float outv = 0.f;
    #pragma unroll
    for (int qi = 0; qi < 8; ++qi) {
        #pragma unroll
        for (int d = 0; d < 8; ++d) {
            float ta = acc[qi][d];
            #pragma unroll
            for (int m = 32; m >= 1; m >>= 1) ta += __shfl_xor(ta, m, 64);
            if (lane == qi*8 + d) outv = ta * rinv[qi];
        }
    }
    O[((size_t)b * 4096 + qbase) * 8 + lane] = outv;  // 64 contiguous floats/wave
}

// =====================================================================
// Kernel 3: second-stage projection (8 -> 8 x3) from feats
// =====================================================================
__global__ __launch_bounds__(256) void proj2_kernel(
    const float* __restrict__ F,
    const float* __restrict__ Wsq, const float* __restrict__ bsq,
    const float* __restrict__ Wsk, const float* __restrict__ bsk,
    const float* __restrict__ Wsv, const float* __restrict__ bsv,
    float* __restrict__ Q, float* __restrict__ K, float* __restrict__ V)
{
    __shared__ float sW[8*24 + 24];
    for (int i = threadIdx.x; i < 8*24 + 24; i += 256) {
        float w;
        if (i < 192) {
            int j = i / 24, c = i % 24;
            w = (c < 8) ? Wsq[j*8 + c] : (c < 16) ? Wsk[j*8 + (c-8)] : Wsv[j*8 + (c-16)];
        } else {
            int c = i - 192;
            w = (c < 8) ? bsq[c] : (c < 16) ? bsk[c-8] : bsv[c-16];
        }
        sW[i] = w;
    }
    __syncthreads();

    int p = blockIdx.x * 256 + threadIdx.x;
    const float* f = F + (size_t)p * 8;
    float fv[8];
    {
        float4 a = ((const float4*)f)[0], c = ((const float4*)f)[1];
        fv[0]=a.x; fv[1]=a.y; fv[2]=a.z; fv[3]=a.w;
        fv[4]=c.x; fv[5]=c.y; fv[6]=c.z; fv[7]=c.w;
    }
    float acc[24];
    #pragma unroll
    for (int o = 0; o < 24; ++o) acc[o] = sW[192 + o];
    #pragma unroll
    for (int j = 0; j < 8; ++j) {
        float fj = fv[j];
        #pragma unroll
        for (int o = 0; o < 24; ++o) acc[o] += fj * sW[j*24 + o];
    }
    size_t base = (size_t)p * 8;
    #pragma unroll
    for (int o = 0; o < 8; ++o) {
        Q[base+o] = acc[o];
        K[base+o] = acc[8+o];
        V[base+o] = acc[16+o];
    }
}

// =====================================================================
// Kernel 5: LayerNorm(8) + proj to 3 + clamped softplus + 8x upsample
// thread per patch; writes 8 rows x 24 floats (float4-vectorized)
// =====================================================================
__global__ __launch_bounds__(256) void head_kernel(
    const float* __restrict__ S,
    const float* __restrict__ ln_w, const float* __restrict__ ln_b,
    const float* __restrict__ Wp, const float* __restrict__ bp,
    float* __restrict__ out)
{
    int p = blockIdx.x * 256 + threadIdx.x;
    int b    = p >> 12;
    int pidx = p & 4095;
    int pr = pidx >> 6, pc = pidx & 63;

    const float* s = S + (size_t)p * 8;
    float f[8];
    {
        float4 a = ((const float4*)s)[0], c = ((const float4*)s)[1];
        f[0]=a.x; f[1]=a.y; f[2]=a.z; f[3]=a.w;
        f[4]=c.x; f[5]=c.y; f[6]=c.z; f[7]=c.w;
    }
    float mu = 0.f;
    #pragma unroll
    for (int d = 0; d < 8; ++d) mu += f[d];
    mu *= 0.125f;
    float var = 0.f;
    #pragma unroll
    for (int d = 0; d < 8; ++d) { float t = f[d]-mu; var += t*t; }
    var *= 0.125f;
    float r = rsqrtf(var + 1e-5f);

    float o0 = bp[0], o1 = bp[1], o2 = bp[2];
    #pragma unroll
    for (int d = 0; d < 8; ++d) {
        float n = (f[d]-mu)*r*ln_w[d] + ln_b[d];
        o0 += n*Wp[d*3+0]; o1 += n*Wp[d*3+1]; o2 += n*Wp[d*3+2];
    }
    float o[3] = {o0, o1, o2};
    #pragma unroll
    for (int cix = 0; cix < 3; ++cix) {
        float xx = o[cix];
        float sp = fmaxf(xx, 0.f) + log1pf(expf(-fabsf(xx)));  // stable softplus
        o[cix] = fminf(sp, 6.0f) + 1e-6f;
    }

    float4 f40 = make_float4(o[0], o[1], o[2], o[0]);
    float4 f41 = make_float4(o[1], o[2], o[0], o[1]);
    float4 f42 = make_float4(o[2], o[0], o[1], o[2]);
    float* ob = out + (((size_t)(b*512 + pr*8)) * 512 + (size_t)pc*8) * 3;
    #pragma unroll
    for (int i = 0; i < 8; ++i) {
        float4* row = (float4*)(ob + (size_t)i * 512 * 3);
        row[0]=f40; row[1]=f41; row[2]=f42; row[3]=f40; row[4]=f41; row[5]=f42;
    }
}

// =====================================================================
extern "C" void kernel_launch(void* const* d_in, const int* in_sizes, int n_in,
                              void* d_out, int out_size, void* d_ws, size_t ws_size,
                              hipStream_t stream)
{
    const float* x   = (const float*)d_in[0];
    const float* Wq  = (const float*)d_in[1];
    const float* bq  = (const float*)d_in[2];
    const float* Wk  = (const float*)d_in[3];
    const float* bk  = (const float*)d_in[4];
    const float* Wv  = (const float*)d_in[5];
    const float* bv  = (const float*)d_in[6];
    const float* Wsq = (const float*)d_in[7];
    const float* bsq = (const float*)d_in[8];
    const float* Wsk = (const float*)d_in[9];
    const float* bsk = (const float*)d_in[10];
    const float* Wsv = (const float*)d_in[11];
    const float* bsv = (const float*)d_in[12];
    const float* lnw = (const float*)d_in[13];
    const float* lnb = (const float*)d_in[14];
    const float* Wp  = (const float*)d_in[15];
    const float* bp  = (const float*)d_in[16];
    float* out = (float*)d_out;

    // workspace: 4 buffers of 32768*8 floats (1 MB each)
    float* A = (float*)d_ws;        // Q  then Q2
    float* B = A + 262144;          // K  then K2
    float* C = B + 262144;          // V  then V2
    float* D = C + 262144;          // feats then sig

    qkv_kernel <<<128, 256, 0, stream>>>(x, Wq, bq, Wk, bk, Wv, bv, A, B, C);
    attn_kernel<<<1024, 256, 0, stream>>>(A, B, C, D);
    proj2_kernel<<<128, 256, 0, stream>>>(D, Wsq, bsq, Wsk, bsk, Wsv, bsv, A, B, C);
    attn_kernel<<<1024, 256, 0, stream>>>(A, B, C, D);
    head_kernel<<<128, 256, 0, stream>>>(D, lnw, lnb, Wp, bp, out);
}